// Round 2
// baseline (4702.906 us; speedup 1.0000x reference)
//
#include <hip/hip_runtime.h>
#include <hip/hip_bf16.h>

#define HEADS 2

// Load element i of p as float, where p is either f32 (isf32=1) or bf16 bits (isf32=0).
__device__ __forceinline__ float ldany(const void* __restrict__ p, size_t i, int isf32) {
  if (isf32) return ((const float*)p)[i];
  unsigned int u = ((const unsigned short*)p)[i];
  return __uint_as_float(u << 16);
}

// Detect input float dtype: interpret first 256 elements of x as bf16 bit patterns.
// True bf16 N(0,1) data: exponent field <= ~130. f32 data misread as bf16: even
// elements are mantissa byte-pairs -> uniform exponent field -> max >> 160.
__global__ void detect_dtype(const unsigned short* __restrict__ xb, int* __restrict__ flag) {
  if (blockIdx.x == 0 && threadIdx.x == 0) {
    int mx = 0;
    for (int i = 0; i < 256; ++i) { int e = (xb[i] >> 7) & 0xFF; if (e > mx) mx = e; }
    *flag = (mx > 160) ? 1 : 0;   // 1 => inputs are float32
  }
}

// ---------------- Kernel 1: per-node projection + attention logits ----------------
template<int FIN, int C, bool IN_SCRATCH_F32>
__global__ void gat_node_proj(const void* __restrict__ xin,
                              const void* __restrict__ Wg,
                              const void* __restrict__ asg,
                              const void* __restrict__ adg,
                              float* __restrict__ h,
                              float* __restrict__ als,
                              float* __restrict__ ald,
                              int n, const int* __restrict__ flag) {
  const int isf = *flag;
  constexpr int FOUT = HEADS * C;
  __shared__ float Ws[FIN * FOUT];
  __shared__ float as_s[FOUT], ad_s[FOUT];
  for (int i = threadIdx.x; i < FIN * FOUT; i += blockDim.x) Ws[i] = ldany(Wg, i, isf);
  if (threadIdx.x < FOUT) {
    as_s[threadIdx.x] = ldany(asg, threadIdx.x, isf);
    ad_s[threadIdx.x] = ldany(adg, threadIdx.x, isf);
  }
  __syncthreads();
  int nid = blockIdx.x * blockDim.x + threadIdx.x;
  if (nid >= n) return;

  float xr[FIN];
  #pragma unroll
  for (int i = 0; i < FIN; ++i)
    xr[i] = IN_SCRATCH_F32 ? ((const float*)xin)[(size_t)nid * FIN + i]
                           : ldany(xin, (size_t)nid * FIN + i, isf);

  float hv[FOUT];
  #pragma unroll
  for (int j = 0; j < FOUT; ++j) hv[j] = 0.f;
  #pragma unroll
  for (int k = 0; k < FIN; ++k) {
    #pragma unroll
    for (int j = 0; j < FOUT; ++j) hv[j] += xr[k] * Ws[k * FOUT + j];
  }

  float* hp = h + (size_t)nid * FOUT;
  #pragma unroll
  for (int j = 0; j < FOUT; ++j) hp[j] = hv[j];

  #pragma unroll
  for (int hh = 0; hh < HEADS; ++hh) {
    float s = 0.f, dd = 0.f;
    #pragma unroll
    for (int c = 0; c < C; ++c) {
      s  += hv[hh * C + c] * as_s[hh * C + c];
      dd += hv[hh * C + c] * ad_s[hh * C + c];
    }
    als[(size_t)nid * HEADS + hh] = s;
    ald[(size_t)nid * HEADS + hh] = dd;
  }
}

// ---------------- Kernel 2: edge pass (shift-free softmax, deferred normalize) ----
template<int C>
__global__ void gat_edge_accum(const int* __restrict__ ei, int E, int Et,
                               const float* __restrict__ als,
                               const float* __restrict__ ald,
                               const float* __restrict__ h,
                               float* __restrict__ z,
                               float* __restrict__ num) {
  int e = blockIdx.x * blockDim.x + threadIdx.x;
  if (e >= Et) return;
  int s, d;
  if (e < E) { s = ei[e]; d = ei[E + e]; }
  else       { s = e - E; d = s; }        // self-loop tail
  constexpr int FOUT = HEADS * C;
  float w[HEADS];
  #pragma unroll
  for (int hh = 0; hh < HEADS; ++hh) {
    float lg = als[(size_t)s * HEADS + hh] + ald[(size_t)d * HEADS + hh];
    lg = lg > 0.f ? lg : 0.2f * lg;       // leaky_relu slope 0.2
    w[hh] = __expf(lg);
    atomicAdd(&z[(size_t)d * HEADS + hh], w[hh]);
  }
  const float* hs = h + (size_t)s * FOUT;
  float* nd = num + (size_t)d * FOUT;
  #pragma unroll
  for (int j = 0; j < FOUT; ++j)
    atomicAdd(&nd[j], w[j / C] * hs[j]);
}

// ---------------- Kernel 3: per-node finalize: divide, bias, (ELU | store) -------
template<int C, bool DO_ELU, bool TO_DOUT>
__global__ void gat_node_final(const float* __restrict__ num,
                               const float* __restrict__ z,
                               const void* __restrict__ b,
                               void* __restrict__ outp, int n,
                               const int* __restrict__ flag) {
  const int isf = *flag;
  constexpr int FOUT = HEADS * C;
  int nid = blockIdx.x * blockDim.x + threadIdx.x;
  if (nid >= n) return;
  float zi[HEADS];
  #pragma unroll
  for (int hh = 0; hh < HEADS; ++hh)
    zi[hh] = 1.f / (z[(size_t)nid * HEADS + hh] + 1e-16f);
  #pragma unroll
  for (int j = 0; j < FOUT; ++j) {
    float v = num[(size_t)nid * FOUT + j] * zi[j / C] + ldany(b, j, isf);
    if constexpr (DO_ELU) v = v > 0.f ? v : expm1f(v);
    if constexpr (TO_DOUT) {
      if (isf) ((float*)outp)[(size_t)nid * FOUT + j] = v;
      else     ((__hip_bfloat16*)outp)[(size_t)nid * FOUT + j] = __float2bfloat16(v);
    } else {
      ((float*)outp)[(size_t)nid * FOUT + j] = v;
    }
  }
}

extern "C" void kernel_launch(void* const* d_in, const int* in_sizes, int n_in,
                              void* d_out, int out_size, void* d_ws, size_t ws_size,
                              hipStream_t stream) {
  const void* x   = d_in[0];
  const int*  ei  = (const int*)d_in[1];
  const void* W1  = d_in[2];
  const void* as1 = d_in[3];
  const void* ad1 = d_in[4];
  const void* b1  = d_in[5];
  const void* W2  = d_in[6];
  const void* as2 = d_in[7];
  const void* ad2 = d_in[8];
  const void* b2  = d_in[9];

  const int n  = in_sizes[0] / 16;   // 100000
  const int E  = in_sizes[1] / 2;    // 3200000
  const int Et = E + n;              // + self-loops

  // ws layout: [0..16) flag/header, then arrays (floats). Total 16 + 38n floats.
  int*   flag = (int*)d_ws;
  float* ws   = (float*)d_ws + 16;
  float* h1   = ws;                          // 16n
  float* als1 = ws + (size_t)n * 16;         // 2n
  float* ald1 = ws + (size_t)n * 18;         // 2n
  float* z1   = ws + (size_t)n * 20;         // 2n
  float* num1 = ws + (size_t)n * 22;         // 16n  (finalized in place -> out1)
  float* out1 = num1;
  float* h2   = ws;                          // 8n (reuse)
  float* als2 = ws + (size_t)n * 8;          // 2n
  float* ald2 = ws + (size_t)n * 10;         // 2n
  float* z2   = ws + (size_t)n * 12;         // 2n
  float* num2 = ws + (size_t)n * 14;         // 8n (ends at 22n = start of out1)

  const int TB = 256;
  const int nblk = (n + TB - 1) / TB;
  const int eblk = (Et + TB - 1) / TB;

  detect_dtype<<<1, 64, 0, stream>>>((const unsigned short*)x, flag);

  // -------- Layer 1: 16 -> 8 x 2 heads, ELU --------
  hipMemsetAsync(z1, 0, (size_t)n * 18 * sizeof(float), stream);  // z1 + num1
  gat_node_proj<16, 8, false><<<nblk, TB, 0, stream>>>(x, W1, as1, ad1, h1, als1, ald1, n, flag);
  gat_edge_accum<8><<<eblk, TB, 0, stream>>>(ei, E, Et, als1, ald1, h1, z1, num1);
  gat_node_final<8, true, false><<<nblk, TB, 0, stream>>>(num1, z1, b1, out1, n, flag);

  // -------- Layer 2: 16 -> 4 x 2 heads --------
  hipMemsetAsync(z2, 0, (size_t)n * 10 * sizeof(float), stream);  // z2 + num2
  gat_node_proj<16, 4, true><<<nblk, TB, 0, stream>>>(out1, W2, as2, ad2, h2, als2, ald2, n, flag);
  gat_edge_accum<4><<<eblk, TB, 0, stream>>>(ei, E, Et, als2, ald2, h2, z2, num2);
  gat_node_final<4, false, true><<<nblk, TB, 0, stream>>>(num2, z2, b2, d_out, n, flag);
}

// Round 3
// 537.787 us; speedup vs baseline: 8.7449x; 8.7449x over previous
//
#include <hip/hip_runtime.h>
#include <hip/hip_bf16.h>

#define HEADS 2

// Load element i of p as float, where p is either f32 (isf32=1) or bf16 bits (isf32=0).
__device__ __forceinline__ float ldany(const void* __restrict__ p, size_t i, int isf32) {
  if (isf32) return ((const float*)p)[i];
  unsigned int u = ((const unsigned short*)p)[i];
  return __uint_as_float(u << 16);
}

// Detect input float dtype (see round-1 notes): bf16 N(0,1) exponent field <= ~130;
// f32 misread as bf16 gives uniform-random exponents, max >> 160 over 256 samples.
__global__ void detect_dtype(const unsigned short* __restrict__ xb, int* __restrict__ flag) {
  if (blockIdx.x == 0 && threadIdx.x == 0) {
    int mx = 0;
    for (int i = 0; i < 256; ++i) { int e = (xb[i] >> 7) & 0xFF; if (e > mx) mx = e; }
    *flag = (mx > 160) ? 1 : 0;   // 1 => inputs are float32
  }
}

// ---------------- CSR build ----------------
__global__ void k_hist(const int* __restrict__ ei, int E, int Et, int* __restrict__ deg) {
  int e = blockIdx.x * blockDim.x + threadIdx.x;
  if (e >= Et) return;
  int d = (e < E) ? ei[E + e] : (e - E);
  atomicAdd(&deg[d], 1);
}

// Block-wise exclusive scan: 256 threads x 4 elems = 1024/block.
__global__ void k_scan_blocks(const int* __restrict__ in, int* __restrict__ out,
                              int* __restrict__ bsum, int n) {
  __shared__ int sh[256];
  int tid = threadIdx.x;
  int base = blockIdx.x * 1024 + tid * 4;
  int v0 = 0, v1 = 0, v2 = 0, v3 = 0;
  if (base + 0 < n) v0 = in[base + 0];
  if (base + 1 < n) v1 = in[base + 1];
  if (base + 2 < n) v2 = in[base + 2];
  if (base + 3 < n) v3 = in[base + 3];
  int tsum = v0 + v1 + v2 + v3;
  sh[tid] = tsum;
  __syncthreads();
  for (int off = 1; off < 256; off <<= 1) {
    int t = (tid >= off) ? sh[tid - off] : 0;
    __syncthreads();
    sh[tid] += t;
    __syncthreads();
  }
  int run = sh[tid] - tsum;  // exclusive prefix for this thread
  if (base + 0 < n) out[base + 0] = run;  run += v0;
  if (base + 1 < n) out[base + 1] = run;  run += v1;
  if (base + 2 < n) out[base + 2] = run;  run += v2;
  if (base + 3 < n) out[base + 3] = run;
  if (tid == 255) bsum[blockIdx.x] = sh[255];
}

// Exclusive scan of block sums (B <= 1024), single block of 1024 threads.
__global__ void k_scan_bsum(int* __restrict__ bsum, int B) {
  __shared__ int sh[1024];
  int tid = threadIdx.x;
  int v = (tid < B) ? bsum[tid] : 0;
  sh[tid] = v;
  __syncthreads();
  for (int off = 1; off < 1024; off <<= 1) {
    int t = (tid >= off) ? sh[tid - off] : 0;
    __syncthreads();
    sh[tid] += t;
    __syncthreads();
  }
  if (tid < B) bsum[tid] = sh[tid] - v;
}

__global__ void k_add_offsets(int* __restrict__ out, const int* __restrict__ bsum,
                              int n, int Et) {
  int base = blockIdx.x * 1024 + threadIdx.x * 4;
  int add = bsum[blockIdx.x];
  #pragma unroll
  for (int i = 0; i < 4; ++i)
    if (base + i < n) out[base + i] += add;
  if (blockIdx.x == 0 && threadIdx.x == 0) out[n] = Et;
}

__global__ void k_scatter(const int* __restrict__ ei, int E, int Et,
                          const int* __restrict__ rowptr, int* __restrict__ cur,
                          int* __restrict__ csr) {
  int e = blockIdx.x * blockDim.x + threadIdx.x;
  if (e >= Et) return;
  int s, d;
  if (e < E) { s = ei[e]; d = ei[E + e]; }
  else       { s = e - E; d = s; }
  int pos = rowptr[d] + atomicAdd(&cur[d], 1);
  csr[pos] = s;
}

// ---------------- Projection: h = x@W, per-head interleaved row [h(C), als] ------
// Row layout: node nid at hals + nid*RS; head hh at +hh*HB; floats [0..C)=h, [C]=als.
template<int FIN, int C, int RS, int HB, bool SCRATCH_F32>
__global__ void gat_node_proj(const void* __restrict__ xin,
                              const void* __restrict__ Wg,
                              const void* __restrict__ asg,
                              const void* __restrict__ adg,
                              float* __restrict__ hals,
                              float* __restrict__ ald,
                              int n, const int* __restrict__ flag) {
  const int isf = *flag;
  constexpr int FOUT = HEADS * C;
  __shared__ float Ws[FIN * FOUT];
  __shared__ float as_s[FOUT], ad_s[FOUT];
  for (int i = threadIdx.x; i < FIN * FOUT; i += blockDim.x) Ws[i] = ldany(Wg, i, isf);
  if (threadIdx.x < FOUT) {
    as_s[threadIdx.x] = ldany(asg, threadIdx.x, isf);
    ad_s[threadIdx.x] = ldany(adg, threadIdx.x, isf);
  }
  __syncthreads();
  int nid = blockIdx.x * blockDim.x + threadIdx.x;
  if (nid >= n) return;

  float xr[FIN];
  #pragma unroll
  for (int i = 0; i < FIN; ++i)
    xr[i] = SCRATCH_F32 ? ((const float*)xin)[(size_t)nid * FIN + i]
                        : ldany(xin, (size_t)nid * FIN + i, isf);

  float hv[FOUT];
  #pragma unroll
  for (int j = 0; j < FOUT; ++j) hv[j] = 0.f;
  #pragma unroll
  for (int k = 0; k < FIN; ++k) {
    #pragma unroll
    for (int j = 0; j < FOUT; ++j) hv[j] += xr[k] * Ws[k * FOUT + j];
  }

  float* row = hals + (size_t)nid * RS;
  #pragma unroll
  for (int hh = 0; hh < HEADS; ++hh) {
    float s = 0.f, dd = 0.f;
    #pragma unroll
    for (int c = 0; c < C; ++c) {
      row[hh * HB + c] = hv[hh * C + c];
      s  += hv[hh * C + c] * as_s[hh * C + c];
      dd += hv[hh * C + c] * ad_s[hh * C + c];
    }
    row[hh * HB + C] = s;
    ald[(size_t)nid * HEADS + hh] = dd;
  }
}

// ---------------- Fused gather + softmax-normalize + bias (+ELU) + store ---------
// Thread t = (nid, head). Walks CSR segment, accumulates w*h and z in registers.
template<int C, int RS, int HB, bool DO_ELU, bool TO_DOUT>
__global__ void gat_gather(const int* __restrict__ rowptr,
                           const int* __restrict__ csr,
                           const float* __restrict__ hals,
                           const float* __restrict__ ald,
                           const void* __restrict__ b,
                           void* __restrict__ outp,
                           int n, const int* __restrict__ flag) {
  const int isf = *flag;
  constexpr int FOUT = HEADS * C;
  int t = blockIdx.x * blockDim.x + threadIdx.x;
  if (t >= 2 * n) return;
  int nid = t >> 1, hh = t & 1;
  int beg = rowptr[nid], end = rowptr[nid + 1];
  float aldd = ald[(size_t)nid * HEADS + hh];

  float acc[C];
  #pragma unroll
  for (int c = 0; c < C; ++c) acc[c] = 0.f;
  float z = 0.f;

  for (int k = beg; k < end; ++k) {
    int s = csr[k];
    const float4* r4 = (const float4*)(hals + (size_t)s * RS + hh * HB);
    float hv[C];
    #pragma unroll
    for (int q = 0; q < C / 4; ++q) {
      float4 f = r4[q];
      hv[4 * q + 0] = f.x; hv[4 * q + 1] = f.y;
      hv[4 * q + 2] = f.z; hv[4 * q + 3] = f.w;
    }
    float lg = ((const float*)r4)[C] + aldd;
    lg = lg > 0.f ? lg : 0.2f * lg;       // leaky_relu slope 0.2
    float w = __expf(lg);
    z += w;
    #pragma unroll
    for (int c = 0; c < C; ++c) acc[c] += w * hv[c];
  }

  float inv = 1.f / (z + 1e-16f);
  #pragma unroll
  for (int c = 0; c < C; ++c) {
    float v = acc[c] * inv + ldany(b, hh * C + c, isf);
    if constexpr (DO_ELU) v = v > 0.f ? v : expm1f(v);
    size_t oi = (size_t)nid * FOUT + hh * C + c;
    if constexpr (TO_DOUT) {
      if (isf) ((float*)outp)[oi] = v;
      else     ((__hip_bfloat16*)outp)[oi] = __float2bfloat16(v);
    } else {
      ((float*)outp)[oi] = v;
    }
  }
}

extern "C" void kernel_launch(void* const* d_in, const int* in_sizes, int n_in,
                              void* d_out, int out_size, void* d_ws, size_t ws_size,
                              hipStream_t stream) {
  const void* x   = d_in[0];
  const int*  ei  = (const int*)d_in[1];
  const void* W1  = d_in[2];
  const void* as1 = d_in[3];
  const void* ad1 = d_in[4];
  const void* b1  = d_in[5];
  const void* W2  = d_in[6];
  const void* as2 = d_in[7];
  const void* ad2 = d_in[8];
  const void* b2  = d_in[9];

  const int n  = in_sizes[0] / 16;   // 100000
  const int E  = in_sizes[1] / 2;    // 3200000
  const int Et = E + n;              // + self-loops

  // ---- workspace layout ----
  char* base = (char*)d_ws;
  int*  flag   = (int*)base;                       // 64 B
  int*  deg    = (int*)(base + 64);                // n+1 ints (also scatter cursor)
  int*  rowptr = deg + (n + 1);                    // n+1 ints
  int*  bsum   = rowptr + (n + 1);                 // 1024 ints
  int*  csr    = bsum + 1024;                      // Et ints
  size_t foff = 64 + sizeof(int) * ((size_t)(n + 1) * 2 + 1024 + (size_t)Et);
  foff = (foff + 63) & ~(size_t)63;
  float* hals = (float*)(base + foff);             // 24n floats (L1) / 16n (L2 reuse)
  float* ald  = hals + (size_t)24 * n;             // 2n
  float* out1 = ald + (size_t)2 * n;               // 16n

  const int TB   = 256;
  const int nblk = (n + TB - 1) / TB;
  const int eblk = (Et + TB - 1) / TB;
  const int gblk = (2 * n + TB - 1) / TB;
  const int SB   = (n + 1023) / 1024;              // scan blocks (98)

  detect_dtype<<<1, 64, 0, stream>>>((const unsigned short*)x, flag);

  // ---- CSR build (once; shared by both layers) ----
  hipMemsetAsync(deg, 0, (size_t)(n + 1) * sizeof(int), stream);
  k_hist<<<eblk, TB, 0, stream>>>(ei, E, Et, deg);
  k_scan_blocks<<<SB, TB, 0, stream>>>(deg, rowptr, bsum, n);
  k_scan_bsum<<<1, 1024, 0, stream>>>(bsum, SB);
  k_add_offsets<<<SB, TB, 0, stream>>>(rowptr, bsum, n, Et);
  hipMemsetAsync(deg, 0, (size_t)(n + 1) * sizeof(int), stream);  // -> cursor
  k_scatter<<<eblk, TB, 0, stream>>>(ei, E, Et, rowptr, deg, csr);

  // ---- Layer 1: 16 -> 8 x 2 heads, ELU ----  (row stride 24 floats, head stride 12)
  gat_node_proj<16, 8, 24, 12, false><<<nblk, TB, 0, stream>>>(x, W1, as1, ad1, hals, ald, n, flag);
  gat_gather<8, 24, 12, true, false><<<gblk, TB, 0, stream>>>(rowptr, csr, hals, ald, b1, out1, n, flag);

  // ---- Layer 2: 16 -> 4 x 2 heads ----       (row stride 16 floats, head stride 8)
  gat_node_proj<16, 4, 16, 8, true><<<nblk, TB, 0, stream>>>(out1, W2, as2, ad2, hals, ald, n, flag);
  gat_gather<4, 16, 8, false, true><<<gblk, TB, 0, stream>>>(rowptr, csr, hals, ald, b2, d_out, n, flag);
}